// Round 9
// baseline (261.804 us; speedup 1.0000x reference)
//
#include <hip/hip_runtime.h>
#include <hip/hip_bf16.h>
#include <math.h>

// Problem constants (B,S,H fixed by setup_inputs)
constexpr int Bc = 4, Sc = 2048, Hc = 1024, NHc = 16, DKc = 64;

// Workspace layout (float units).
constexpr size_t XHOFF = 0;                 // x bf16: 8,388,608 shorts
constexpr size_t QOFF  = 4194304;           // Q bf16 (bh,s,d)
constexpr size_t KOFF  = 8388608;           // K bf16 (bh,s,d)
constexpr size_t WQOFF = 12582912;          // Wq bf16 (pre-scaled 0.125*log2e)
constexpr size_t WKOFF = 13107200;          // Wk bf16
constexpr size_t LIOFF = 13631488;          // 1/rowsum per (bh,q)
constexpr size_t WOFF  = 13762560;          // attn column sums per (bh,k)
constexpr size_t YOFF  = 13893632;          // y[b,h,j] fp32 (4*16*1024)
constexpr size_t CSOFF = 13959168;          // csum[b,n] (4*1024)
constexpr size_t YPOFF = 13963264;          // y partials: 16 chunks x 65536

typedef __attribute__((ext_vector_type(8))) short bf16x8;  // 8 bf16 (4 VGPRs)
typedef __attribute__((ext_vector_type(4))) float f32x4;

__device__ inline short f2bf(float v) {
    __hip_bfloat16 h = __float2bfloat16(v);
    return *reinterpret_cast<short*>(&h);
}

// raw 2^x (v_exp_f32). Scores are pre-scaled by log2(e) via Wq, so
// ex2(score) == exp(score_unscaled).
__device__ inline float ex2(float x) {
#if defined(__has_builtin) && __has_builtin(__builtin_amdgcn_exp2f)
    return __builtin_amdgcn_exp2f(x);
#else
    float r; asm("v_exp_f32 %0, %1" : "=v"(r) : "v"(x)); return r;
#endif
}

__device__ inline void gld_lds16(const void* g, void* l) {
    __builtin_amdgcn_global_load_lds(
        (const __attribute__((address_space(1))) unsigned int*)g,
        (__attribute__((address_space(3))) unsigned int*)l, 16, 0, 0);
}

// ---------------------------------------------------------------------------
// Kernel 0: fused fp32 -> bf16 conversion of x / Wq(x0.125*log2e) / Wk.
// ---------------------------------------------------------------------------
__global__ __launch_bounds__(256) void cvt_all_kernel(
    const float* __restrict__ x, const float* __restrict__ Wq,
    const float* __restrict__ Wk, float* __restrict__ ws)
{
    const size_t i = ((size_t)blockIdx.x * 256 + threadIdx.x) * 8;
    const float* src; short* dst; float scale; size_t off;
    constexpr float QSC = 0.125f * 1.44269504088896340736f;  // 1/sqrt(dk) * log2(e)
    if (i < 8388608)       { src = x;  dst = (short*)(ws + XHOFF); off = i;            scale = 1.0f; }
    else if (i < 9437184)  { src = Wq; dst = (short*)(ws + WQOFF); off = i - 8388608;  scale = QSC;  }
    else                   { src = Wk; dst = (short*)(ws + WKOFF); off = i - 9437184;  scale = 1.0f; }
    float4 a = *(const float4*)(src + off);
    float4 b = *(const float4*)(src + off + 4);
    bf16x8 o;
    o[0] = f2bf(a.x * scale); o[1] = f2bf(a.y * scale);
    o[2] = f2bf(a.z * scale); o[3] = f2bf(a.w * scale);
    o[4] = f2bf(b.x * scale); o[5] = f2bf(b.y * scale);
    o[6] = f2bf(b.z * scale); o[7] = f2bf(b.w * scale);
    *(bf16x8*)(dst + off) = o;
}

// ---------------------------------------------------------------------------
// Kernel 1: Q/K projections, bf16 MFMA, m97-style 128x128 tile.
// ---------------------------------------------------------------------------
__global__ __launch_bounds__(256) void proj_mfma_kernel(
    const int* __restrict__ L, float* __restrict__ ws)
{
    const int z  = blockIdx.z;
    const int m0 = blockIdx.y * 128;
    const int n0 = blockIdx.x * 128;
    const int b  = m0 >> 11;
    const int s0 = m0 & 2047;
    const int Lb = L[b];
    if (s0 >= Lb) return;

    const short* __restrict__ A = (const short*)(ws + XHOFF);
    const short* __restrict__ W = (const short*)(ws + (z == 0 ? WQOFF : WKOFF));
    short* __restrict__ Out = (short*)(ws + (z == 0 ? QOFF : KOFF));

    __shared__ __align__(16) short As[128 * 32];
    __shared__ __align__(16) short Bs[128 * 32];

    const int tid  = threadIdx.x;
    const int lane = tid & 63;
    const int wave = tid >> 6;
    const int l16  = lane & 15, quad = lane >> 4;
    const int wm = (wave & 1) * 64, wn = (wave >> 1) * 64;

    const int c0 = tid, c1 = tid + 256;
    const int r0 = c0 >> 2, g0 = (c0 & 3) * 8;
    const int r1 = c1 >> 2, g1 = (c1 & 3) * 8;
    short* lA0 = As + wave * 512;
    short* lA1 = As + 2048 + wave * 512;
    short* lB0 = Bs + wave * 512;
    short* lB1 = Bs + 2048 + wave * 512;

    const f32x4 z4 = {0.f, 0.f, 0.f, 0.f};
    f32x4 acc[4][4];
    #pragma unroll
    for (int i = 0; i < 4; ++i)
        #pragma unroll
        for (int j = 0; j < 4; ++j) acc[i][j] = z4;

    for (int k0 = 0; k0 < Hc; k0 += 32) {
        __syncthreads();
        gld_lds16(A + (size_t)(m0 + r0) * Hc + k0 + g0, lA0);
        gld_lds16(A + (size_t)(m0 + r1) * Hc + k0 + g1, lA1);
        gld_lds16(W + (size_t)(n0 + r0) * Hc + k0 + g0, lB0);
        gld_lds16(W + (size_t)(n0 + r1) * Hc + k0 + g1, lB1);
        __syncthreads();

        bf16x8 af[4], bfr[4];
        #pragma unroll
        for (int mt = 0; mt < 4; ++mt)
            af[mt] = *(const bf16x8*)(As + (wm + mt * 16 + l16) * 32 + quad * 8);
        #pragma unroll
        for (int nt = 0; nt < 4; ++nt)
            bfr[nt] = *(const bf16x8*)(Bs + (wn + nt * 16 + l16) * 32 + quad * 8);
        #pragma unroll
        for (int mt = 0; mt < 4; ++mt)
            #pragma unroll
            for (int nt = 0; nt < 4; ++nt)
                acc[mt][nt] = __builtin_amdgcn_mfma_f32_16x16x32_bf16(
                    af[mt], bfr[nt], acc[mt][nt], 0, 0, 0);
    }

    #pragma unroll
    for (int mt = 0; mt < 4; ++mt) {
        #pragma unroll
        for (int nt = 0; nt < 4; ++nt) {
            const int n = n0 + wn + nt * 16 + l16;
            const int h = n >> 6, d = n & 63;
            #pragma unroll
            for (int r = 0; r < 4; ++r) {
                const int s = s0 + wm + mt * 16 + quad * 4 + r;
                Out[(((size_t)b * NHc + h) * Sc + s) * DKc + d] =
                    f2bf(acc[mt][nt][r]);
            }
        }
    }
}

// ---------------------------------------------------------------------------
// Kernel 2: rowsum -> li. BARRIER-FREE wave-private pipeline: each wave owns
// a 3-buffer ring of 32-row K tiles (4KB each) in LDS, staged with
// global_load_lds 3 tiles ahead and synchronized ONLY by per-wave counted
// s_waitcnt vmcnt(8) (never 0 mid-loop, no __syncthreads). Each wave hoists
// 64 q-rows as 4 fragment groups; per tile: 2 steps x {2 swizzled
// ds_read_b128, 8 MFMA, 16 exp}. One block per (bh, 256-q slab).
// ---------------------------------------------------------------------------
__global__ __launch_bounds__(256) void rowsum_kernel(
    const int* __restrict__ L, float* __restrict__ ws)
{
    const int bh = blockIdx.x;          // 64
    const int qs = blockIdx.y;          // 8 slabs of 256
    const int b  = bh >> 4;
    const int Lb = L[b];
    if (qs * 256 >= Lb) return;

    const int tid  = threadIdx.x;
    const int wave = tid >> 6;
    const int lane = tid & 63;
    const int l16 = lane & 15, quad = lane >> 4;
    const int q0 = qs * 256 + wave * 64;

    const short* __restrict__ qarr = (const short*)(ws + QOFF) + (size_t)bh * Sc * DKc;
    const short* __restrict__ karr = (const short*)(ws + KOFF) + (size_t)bh * Sc * DKc;

    // wave-private buffer ring: 4 waves x 3 bufs x (32 rows x 64 shorts) = 48 KB
    __shared__ __align__(16) short Ks[4][3][32 * 64];

    // staging source pattern (per gld_lds16 instr j, this lane):
    const int srow = lane >> 3;                  // row-within-8 & (row&7)
    const int scol = (lane & 7) ^ srow;          // swizzled chunk
    const short* ksrc = karr + (size_t)srow * DKc + scol * 8;

    // hoist 64 q rows (4 groups of 16) as B-fragments
    bf16x8 bq[4][2];
    #pragma unroll
    for (int g = 0; g < 4; ++g) {
        const short* qr = qarr + (size_t)(q0 + g * 16 + l16) * DKc;
        bq[g][0] = *(const bf16x8*)(qr + quad * 8);
        bq[g][1] = *(const bf16x8*)(qr + 32 + quad * 8);
    }
    float lacc[4] = {0.f, 0.f, 0.f, 0.f};

    const int n = (Lb + 31) >> 5;       // 32-row tiles to stream

    // stage tile t into slot s (4 x gld_lds16, 1KB each)
    auto stage = [&](int s, int kt) {
        short* dst = &Ks[wave][s][0];
        #pragma unroll
        for (int j = 0; j < 4; ++j)
            gld_lds16(ksrc + (size_t)(kt + j * 8) * DKc, dst + j * 512);
    };

    stage(0, 0);
    if (n > 1) stage(1, 32);
    if (n > 2) stage(2, 64);

    int slot = 0;
    for (int t = 0; t < n; ++t) {
        const int kt = t << 5;
        if (t + 2 < n)      asm volatile("s_waitcnt vmcnt(8)" ::: "memory");
        else if (t + 1 < n) asm volatile("s_waitcnt vmcnt(4)" ::: "memory");
        else                asm volatile("s_waitcnt vmcnt(0)" ::: "memory");

        const short* B = &Ks[wave][slot][0];
        if (kt + 32 <= Lb) {
            #pragma unroll
            for (int tt = 0; tt < 2; ++tt) {
                const int r = tt * 16 + l16;
                const bf16x8 alo = *(const bf16x8*)(B + r * 64 + (quad ^ (r & 7)) * 8);
                const bf16x8 ahi = *(const bf16x8*)(B + r * 64 + ((4 + quad) ^ (r & 7)) * 8);
                #pragma unroll
                for (int g = 0; g < 4; ++g) {
                    f32x4 c = {0.f, 0.f, 0.f, 0.f};
                    c = __builtin_amdgcn_mfma_f32_16x16x32_bf16(alo, bq[g][0], c, 0, 0, 0);
                    c = __builtin_amdgcn_mfma_f32_16x16x32_bf16(ahi, bq[g][1], c, 0, 0, 0);
                    lacc[g] += (ex2(c[0]) + ex2(c[1])) + (ex2(c[2]) + ex2(c[3]));
                }
            }
        } else {
            // boundary tile: mask k >= Lb (select after exp; stale rows dropped)
            #pragma unroll
            for (int tt = 0; tt < 2; ++tt) {
                const int r = tt * 16 + l16;
                const bf16x8 alo = *(const bf16x8*)(B + r * 64 + (quad ^ (r & 7)) * 8);
                const bf16x8 ahi = *(const bf16x8*)(B + r * 64 + ((4 + quad) ^ (r & 7)) * 8);
                #pragma unroll
                for (int g = 0; g < 4; ++g) {
                    f32x4 c = {0.f, 0.f, 0.f, 0.f};
                    c = __builtin_amdgcn_mfma_f32_16x16x32_bf16(alo, bq[g][0], c, 0, 0, 0);
                    c = __builtin_amdgcn_mfma_f32_16x16x32_bf16(ahi, bq[g][1], c, 0, 0, 0);
                    #pragma unroll
                    for (int rr = 0; rr < 4; ++rr) {
                        const bool kv = (kt + tt * 16 + quad * 4 + rr) < Lb;
                        lacc[g] += kv ? ex2(c[rr]) : 0.f;
                    }
                }
            }
        }
        if (t + 3 < n) stage(slot, kt + 96);   // refill freed slot
        slot = (slot == 2) ? 0 : slot + 1;
    }

    // sum over quads (k sub-blocks); col l16 is the q index
    #pragma unroll
    for (int g = 0; g < 4; ++g) {
        lacc[g] += __shfl_xor(lacc[g], 16, 64);
        lacc[g] += __shfl_xor(lacc[g], 32, 64);
    }
    float* __restrict__ li = ws + LIOFF + (size_t)bh * Sc;
    #pragma unroll
    for (int g = 0; g < 4; ++g)
        if (quad == g) li[q0 + g * 16 + l16] = 1.0f / lacc[g];
}

// ---------------------------------------------------------------------------
// Kernel 3: colsum -> w. Same wave-private barrier-free pipeline streaming Q;
// the full 2048-entry li array is staged to LDS ONCE at block start (the only
// __syncthreads in the kernel). Each wave hoists 64 k-rows as A-fragments.
// ---------------------------------------------------------------------------
__global__ __launch_bounds__(256) void colsum_kernel(
    const int* __restrict__ L, float* __restrict__ ws)
{
    const int bh = blockIdx.x;          // 64
    const int ks = blockIdx.y;          // 8 slabs of 256
    const int b  = bh >> 4;
    const int Lb = L[b];
    if (ks * 256 >= Lb) return;

    const int tid  = threadIdx.x;
    const int wave = tid >> 6;
    const int lane = tid & 63;
    const int l16 = lane & 15, quad = lane >> 4;
    const int k0 = ks * 256 + wave * 64;

    const short* __restrict__ qarr = (const short*)(ws + QOFF) + (size_t)bh * Sc * DKc;
    const short* __restrict__ karr = (const short*)(ws + KOFF) + (size_t)bh * Sc * DKc;
    const float* __restrict__ liarr = ws + LIOFF + (size_t)bh * Sc;

    __shared__ __align__(16) short Qs[4][3][32 * 64];   // 48 KB ring
    __shared__ __align__(16) float Lis[2048];           // 8 KB, staged once

    // hoist 64 k rows (4 groups of 16) as A-fragments
    bf16x8 ak[4][2];
    #pragma unroll
    for (int g = 0; g < 4; ++g) {
        const short* kr = karr + (size_t)(k0 + g * 16 + l16) * DKc;
        ak[g][0] = *(const bf16x8*)(kr + quad * 8);
        ak[g][1] = *(const bf16x8*)(kr + 32 + quad * 8);
    }

    // stage li (2048 floats): each wave 2 x 1KB
    #pragma unroll
    for (int j2 = 0; j2 < 2; ++j2)
        gld_lds16(liarr + wave * 512 + j2 * 256 + lane * 4,
                  &Lis[wave * 512 + j2 * 256]);
    __syncthreads();   // drains (publishes li); only barrier in this kernel

    const int srow = lane >> 3;
    const int scol = (lane & 7) ^ srow;
    const short* qsrc = qarr + (size_t)srow * DKc + scol * 8;

    f32x4 w[4];
    #pragma unroll
    for (int g = 0; g < 4; ++g) w[g] = (f32x4){0.f, 0.f, 0.f, 0.f};

    const int n = (Lb + 31) >> 5;

    auto stage = [&](int s, int qt) {
        short* dst = &Qs[wave][s][0];
        #pragma unroll
        for (int j = 0; j < 4; ++j)
            gld_lds16(qsrc + (size_t)(qt + j * 8) * DKc, dst + j * 512);
    };

    stage(0, 0);
    if (n > 1) stage(1, 32);
    if (n > 2) stage(2, 64);

    int slot = 0;
    for (int t = 0; t < n; ++t) {
        const int qt = t << 5;
        if (t + 2 < n)      asm volatile("s_waitcnt vmcnt(8)" ::: "memory");
        else if (t + 1 < n) asm volatile("s_waitcnt vmcnt(4)" ::: "memory");
        else                asm volatile("s_waitcnt vmcnt(0)" ::: "memory");

        const short* B = &Qs[wave][slot][0];
        const bool full = (qt + 32 <= Lb);
        #pragma unroll
        for (int tt = 0; tt < 2; ++tt) {
            const int r = tt * 16 + l16;
            const bf16x8 blo = *(const bf16x8*)(B + r * 64 + (quad ^ (r & 7)) * 8);
            const bf16x8 bhi = *(const bf16x8*)(B + r * 64 + ((4 + quad) ^ (r & 7)) * 8);
            const float lv = (full || qt + r < Lb) ? Lis[qt + r] : 0.f;
            #pragma unroll
            for (int g = 0; g < 4; ++g) {
                f32x4 c = {0.f, 0.f, 0.f, 0.f};
                c = __builtin_amdgcn_mfma_f32_16x16x32_bf16(ak[g][0], blo, c, 0, 0, 0);
                c = __builtin_amdgcn_mfma_f32_16x16x32_bf16(ak[g][1], bhi, c, 0, 0, 0);
                #pragma unroll
                for (int rr = 0; rr < 4; ++rr)
                    w[g][rr] += ex2(c[rr]) * lv;
            }
        }
        if (t + 3 < n) stage(slot, qt + 96);
        slot = (slot == 2) ? 0 : slot + 1;
    }

    // sum over l16 (q); row = g*16 + quad*4 + rr is the k index
    #pragma unroll
    for (int off = 1; off <= 8; off <<= 1)
        #pragma unroll
        for (int g = 0; g < 4; ++g)
            #pragma unroll
            for (int rr = 0; rr < 4; ++rr)
                w[g][rr] += __shfl_xor(w[g][rr], off, 64);
    if (l16 == 0) {
        float* __restrict__ warr = ws + WOFF + (size_t)bh * Sc;
        #pragma unroll
        for (int g = 0; g < 4; ++g)
            #pragma unroll
            for (int rr = 0; rr < 4; ++rr)
                warr[k0 + g * 16 + quad * 4 + rr] = w[g][rr];
    }
}

// ---------------------------------------------------------------------------
// Kernel 4a: partial y: yp[c][b,h,j] = sum_{s in chunk c} w[b,h,s]*x[b,s,j].
// ---------------------------------------------------------------------------
__global__ __launch_bounds__(256) void yw_part_kernel(
    const float* __restrict__ x, const int* __restrict__ L,
    float* __restrict__ ws)
{
    const int b  = blockIdx.y;
    const int j0 = blockIdx.x * 64;
    const int s0 = blockIdx.z * 128;
    const int Lb = L[b];
    if (s0 >= Lb) return;
    const int js = threadIdx.x & 63;
    const int sl = threadIdx.x >> 6;
    const float* __restrict__ warr = ws + WOFF + (size_t)b * NHc * Sc;
    const float* __restrict__ xb = x + (size_t)b * Sc * Hc;

    __shared__ float wt[128][20];
    __shared__ float red[4][16][64];

    #pragma unroll
    for (int i = 0; i < 8; ++i) {
        const int s = (threadIdx.x & 15) + 16 * i;
        const int h = threadIdx.x >> 4;
        float v = 0.f;
        if (s0 + s < Lb) v = warr[(size_t)h * Sc + s0 + s];
        wt[s][h] = v;
    }
    __syncthreads();

    float acc[16];
    #pragma unroll
    for (int h = 0; h < 16; ++h) acc[h] = 0.f;

    #pragma unroll 4
    for (int s = sl; s < 128; s += 4) {
        const float xv = xb[(size_t)(s0 + s) * Hc + j0 + js];
        const f32x4 wa = *(const f32x4*)&wt[s][0];
        const f32x4 wb = *(const f32x4*)&wt[s][4];
        const f32x4 wc = *(const f32x4*)&wt[s][8];
        const f32x4 wd = *(const f32x4*)&wt[s][12];
        #pragma unroll
        for (int h = 0; h < 4; ++h) acc[h]      += wa[h] * xv;
        #pragma unroll
        for (int h = 0; h < 4; ++h) acc[4 + h]  += wb[h] * xv;
        #pragma unroll
        for (int h = 0; h < 4; ++h) acc[8 + h]  += wc[h] * xv;
        #pragma unroll
        for (int h = 0; h < 4; ++h) acc[12 + h] += wd[h] * xv;
    }
    #pragma unroll
    for (int h = 0; h < 16; ++h) red[sl][h][js] = acc[h];
    __syncthreads();
    if (sl == 0) {
        float* __restrict__ yp = ws + YPOFF +
            ((size_t)blockIdx.z * Bc * NHc + (size_t)b * NHc) * Hc;
        #pragma unroll
        for (int h = 0; h < 16; ++h)
            yp[(size_t)h * Hc + j0 + js] =
                red[0][h][js] + red[1][h][js] + red[2][h][js] + red[3][h][js];
    }
}

// ---------------------------------------------------------------------------
// Kernel 4b: y[b,h,j] = sum over valid chunks of yp.
// ---------------------------------------------------------------------------
__global__ __launch_bounds__(256) void yw_reduce_kernel(
    const int* __restrict__ L, float* __restrict__ ws)
{
    const int b = blockIdx.y;
    const int i = blockIdx.x * 256 + threadIdx.x;   // over NHc*Hc = 16384
    const int nc = (L[b] + 127) >> 7;
    const float* __restrict__ p = ws + YPOFF + (size_t)b * NHc * Hc + i;
    float acc = 0.f;
    for (int c = 0; c < nc; ++c)
        acc += p[(size_t)c * Bc * NHc * Hc];
    ws[YOFF + (size_t)b * NHc * Hc + i] = acc;
}

// ---------------------------------------------------------------------------
// Kernel 5: csum[b,n] = sum_j y[b,h(n),j]*Wv[n,j] + bv[n]*L[b].
// ---------------------------------------------------------------------------
__global__ __launch_bounds__(256) void csum_kernel(
    const float* __restrict__ Wv, const float* __restrict__ bv,
    const int* __restrict__ L, float* __restrict__ ws)
{
    const int b = blockIdx.y;
    const int h = blockIdx.x;            // n0 = h*64, all in head h
    const int n0 = h * 64;
    const int lane = threadIdx.x & 63;
    const int wave = threadIdx.x >> 6;
    const float Lb = (float)L[b];

    __shared__ float ys[1024];
    const float* __restrict__ y = ws + YOFF + ((size_t)b * NHc + h) * Hc;
    for (int i = threadIdx.x; i < 1024; i += 256) ys[i] = y[i];
    __syncthreads();

    f32x4 yv[4];
    #pragma unroll
    for (int p = 0; p < 4; ++p) yv[p] = *(const f32x4*)&ys[p * 256 + lane * 4];

    #pragma unroll
    for (int r = 0; r < 16; ++r) {
        const int n = n0 + wave * 16 + r;
        const float* wrow = Wv + (size_t)n * Hc;
        float a = 0.f;
        #pragma unroll
        for (int p = 0; p < 4; ++p) {
            const f32x4 wv = *(const f32x4*)(wrow + p * 256 + lane * 4);
            a += wv[0]*yv[p][0] + wv[1]*yv[p][1] + wv[2]*yv[p][2] + wv[3]*yv[p][3];
        }
        #pragma unroll
        for (int off = 32; off > 0; off >>= 1) a += __shfl_xor(a, off, 64);
        if (lane == 0)
            ws[CSOFF + (size_t)b * Hc + n] = a + bv[n] * Lb;
    }
}

// ---------------------------------------------------------------------------
// Kernel 6: pooled[b,o] = (sum_n csum[b,n]*Wo[o,n]) / L[b] + bo[o].
// ---------------------------------------------------------------------------
__global__ __launch_bounds__(256) void out_kernel(
    const float* __restrict__ Wo, const float* __restrict__ bo,
    const int* __restrict__ L, const float* __restrict__ ws,
    float* __restrict__ out)
{
    const int b = blockIdx.y;
    const int o0 = blockIdx.x * 64;
    const int lane = threadIdx.x & 63;
    const int wave = threadIdx.x >> 6;
    const float linv = 1.0f / (float)L[b];

    __shared__ float cs[1024];
    const float* __restrict__ c = ws + CSOFF + (size_t)b * Hc;
    for (int i = threadIdx.x; i < 1024; i += 256) cs[i] = c[i];
    __syncthreads();

    f32x4 cv[4];
    #pragma unroll
    for (int p = 0; p < 4; ++p) cv[p] = *(const f32x4*)&cs[p * 256 + lane * 4];

    #pragma unroll
    for (int r = 0; r < 16; ++r) {
        const int o = o0 + wave * 16 + r;
        const float* wrow = Wo + (size_t)o * Hc;
        float a = 0.f;
        #pragma unroll
        for (int p = 0; p < 4; ++p) {
            const f32x4 wv = *(const f32x4*)(wrow + p * 256 + lane * 4);
            a += wv[0]*cv[p][0] + wv[1]*cv[p][1] + wv[2]*cv[p][2] + wv[3]*cv[p][3];
        }
        #pragma unroll
        for (int off = 32; off > 0; off >>= 1) a += __shfl_xor(a, off, 64);
        if (lane == 0)
            out[(size_t)b * Hc + o] = a * linv + bo[o];
    }
}

// ---------------------------------------------------------------------------
extern "C" void kernel_launch(void* const* d_in, const int* in_sizes, int n_in,
                              void* d_out, int out_size, void* d_ws, size_t ws_size,
                              hipStream_t stream)
{
    (void)in_sizes; (void)n_in; (void)out_size; (void)ws_size;
    const float* x  = (const float*)d_in[0];
    const int*   L  = (const int*)d_in[1];
    const float* Wq = (const float*)d_in[2];
    const float* Wk = (const float*)d_in[3];
    const float* Wv = (const float*)d_in[4];
    const float* bv = (const float*)d_in[5];
    const float* Wo = (const float*)d_in[6];
    const float* bo = (const float*)d_in[7];
    float* out = (float*)d_out;
    float* ws  = (float*)d_ws;

    cvt_all_kernel<<<5120, 256, 0, stream>>>(x, Wq, Wk, ws);

    dim3 gp(Hc / 128, (Bc * Sc) / 128, 2);
    proj_mfma_kernel<<<gp, 256, 0, stream>>>(L, ws);

    dim3 gr(Bc * NHc, Sc / 256);
    rowsum_kernel<<<gr, 256, 0, stream>>>(L, ws);
    colsum_kernel<<<gr, 256, 0, stream>>>(L, ws);

    dim3 gy(Hc / 64, Bc, Sc / 128);
    yw_part_kernel<<<gy, 256, 0, stream>>>(x, L, ws);

    dim3 gyr((NHc * Hc) / 256, Bc);
    yw_reduce_kernel<<<gyr, 256, 0, stream>>>(L, ws);

    dim3 gc(NHc, Bc);
    csum_kernel<<<gc, 256, 0, stream>>>(Wv, bv, L, ws);

    dim3 go(Hc / 64, Bc);
    out_kernel<<<go, 256, 0, stream>>>(Wo, bo, L, ws, out);
}

// Round 10
// 246.250 us; speedup vs baseline: 1.0632x; 1.0632x over previous
//
#include <hip/hip_runtime.h>
#include <hip/hip_bf16.h>
#include <math.h>

// Problem constants (B,S,H fixed by setup_inputs)
constexpr int Bc = 4, Sc = 2048, Hc = 1024, NHc = 16, DKc = 64;

// Workspace layout (float units).
constexpr size_t XHOFF = 0;                 // x bf16: 8,388,608 shorts
constexpr size_t QOFF  = 4194304;           // Q bf16 (bh,s,d)
constexpr size_t KOFF  = 8388608;           // K bf16 (bh,s,d)
constexpr size_t WQOFF = 12582912;          // Wq bf16 (pre-scaled 0.125*log2e)
constexpr size_t WKOFF = 13107200;          // Wk bf16
constexpr size_t LIOFF = 13631488;          // 1/rowsum per (bh,q)
constexpr size_t WOFF  = 13762560;          // attn column sums per (bh,k)
constexpr size_t YOFF  = 13893632;          // y[b,h,j] fp32 (4*16*1024)
constexpr size_t CSOFF = 13959168;          // csum[b,n] (4*1024)
constexpr size_t YPOFF = 13963264;          // y partials: 16 chunks x 65536
constexpr size_t RPOFF = 13963264;          // rowsum partials: 4*64*2048 (aliases YP)
constexpr size_t CPOFF = 13963264;          // colsum partials: 4*64*2048 (aliases RP)

typedef __attribute__((ext_vector_type(8))) short bf16x8;  // 8 bf16 (4 VGPRs)
typedef __attribute__((ext_vector_type(4))) float f32x4;

__device__ inline short f2bf(float v) {
    __hip_bfloat16 h = __float2bfloat16(v);
    return *reinterpret_cast<short*>(&h);
}

// raw 2^x (v_exp_f32). Scores are pre-scaled by log2(e) via Wq, so
// ex2(score) == exp(score_unscaled).
__device__ inline float ex2(float x) {
#if defined(__has_builtin) && __has_builtin(__builtin_amdgcn_exp2f)
    return __builtin_amdgcn_exp2f(x);
#else
    float r; asm("v_exp_f32 %0, %1" : "=v"(r) : "v"(x)); return r;
#endif
}

__device__ inline void gld_lds16(const void* g, void* l) {
    __builtin_amdgcn_global_load_lds(
        (const __attribute__((address_space(1))) unsigned int*)g,
        (__attribute__((address_space(3))) unsigned int*)l, 16, 0, 0);
}

// ---------------------------------------------------------------------------
// Kernel 0: fused fp32 -> bf16 conversion of x / Wq(x0.125*log2e) / Wk.
// ---------------------------------------------------------------------------
__global__ __launch_bounds__(256) void cvt_all_kernel(
    const float* __restrict__ x, const float* __restrict__ Wq,
    const float* __restrict__ Wk, float* __restrict__ ws)
{
    const size_t i = ((size_t)blockIdx.x * 256 + threadIdx.x) * 8;
    const float* src; short* dst; float scale; size_t off;
    constexpr float QSC = 0.125f * 1.44269504088896340736f;  // 1/sqrt(dk) * log2(e)
    if (i < 8388608)       { src = x;  dst = (short*)(ws + XHOFF); off = i;            scale = 1.0f; }
    else if (i < 9437184)  { src = Wq; dst = (short*)(ws + WQOFF); off = i - 8388608;  scale = QSC;  }
    else                   { src = Wk; dst = (short*)(ws + WKOFF); off = i - 9437184;  scale = 1.0f; }
    float4 a = *(const float4*)(src + off);
    float4 b = *(const float4*)(src + off + 4);
    bf16x8 o;
    o[0] = f2bf(a.x * scale); o[1] = f2bf(a.y * scale);
    o[2] = f2bf(a.z * scale); o[3] = f2bf(a.w * scale);
    o[4] = f2bf(b.x * scale); o[5] = f2bf(b.y * scale);
    o[6] = f2bf(b.z * scale); o[7] = f2bf(b.w * scale);
    *(bf16x8*)(dst + off) = o;
}

// ---------------------------------------------------------------------------
// Kernel 1: Q/K projections, bf16 MFMA, m97-style 128x128 tile.
// ---------------------------------------------------------------------------
__global__ __launch_bounds__(256) void proj_mfma_kernel(
    const int* __restrict__ L, float* __restrict__ ws)
{
    const int z  = blockIdx.z;
    const int m0 = blockIdx.y * 128;
    const int n0 = blockIdx.x * 128;
    const int b  = m0 >> 11;
    const int s0 = m0 & 2047;
    const int Lb = L[b];
    if (s0 >= Lb) return;

    const short* __restrict__ A = (const short*)(ws + XHOFF);
    const short* __restrict__ W = (const short*)(ws + (z == 0 ? WQOFF : WKOFF));
    short* __restrict__ Out = (short*)(ws + (z == 0 ? QOFF : KOFF));

    __shared__ __align__(16) short As[128 * 32];
    __shared__ __align__(16) short Bs[128 * 32];

    const int tid  = threadIdx.x;
    const int lane = tid & 63;
    const int wave = tid >> 6;
    const int l16  = lane & 15, quad = lane >> 4;
    const int wm = (wave & 1) * 64, wn = (wave >> 1) * 64;

    const int c0 = tid, c1 = tid + 256;
    const int r0 = c0 >> 2, g0 = (c0 & 3) * 8;
    const int r1 = c1 >> 2, g1 = (c1 & 3) * 8;
    short* lA0 = As + wave * 512;
    short* lA1 = As + 2048 + wave * 512;
    short* lB0 = Bs + wave * 512;
    short* lB1 = Bs + 2048 + wave * 512;

    const f32x4 z4 = {0.f, 0.f, 0.f, 0.f};
    f32x4 acc[4][4];
    #pragma unroll
    for (int i = 0; i < 4; ++i)
        #pragma unroll
        for (int j = 0; j < 4; ++j) acc[i][j] = z4;

    for (int k0 = 0; k0 < Hc; k0 += 32) {
        __syncthreads();
        gld_lds16(A + (size_t)(m0 + r0) * Hc + k0 + g0, lA0);
        gld_lds16(A + (size_t)(m0 + r1) * Hc + k0 + g1, lA1);
        gld_lds16(W + (size_t)(n0 + r0) * Hc + k0 + g0, lB0);
        gld_lds16(W + (size_t)(n0 + r1) * Hc + k0 + g1, lB1);
        __syncthreads();

        bf16x8 af[4], bfr[4];
        #pragma unroll
        for (int mt = 0; mt < 4; ++mt)
            af[mt] = *(const bf16x8*)(As + (wm + mt * 16 + l16) * 32 + quad * 8);
        #pragma unroll
        for (int nt = 0; nt < 4; ++nt)
            bfr[nt] = *(const bf16x8*)(Bs + (wn + nt * 16 + l16) * 32 + quad * 8);
        #pragma unroll
        for (int mt = 0; mt < 4; ++mt)
            #pragma unroll
            for (int nt = 0; nt < 4; ++nt)
                acc[mt][nt] = __builtin_amdgcn_mfma_f32_16x16x32_bf16(
                    af[mt], bfr[nt], acc[mt][nt], 0, 0, 0);
    }

    #pragma unroll
    for (int mt = 0; mt < 4; ++mt) {
        #pragma unroll
        for (int nt = 0; nt < 4; ++nt) {
            const int n = n0 + wn + nt * 16 + l16;
            const int h = n >> 6, d = n & 63;
            #pragma unroll
            for (int r = 0; r < 4; ++r) {
                const int s = s0 + wm + mt * 16 + quad * 4 + r;
                Out[(((size_t)b * NHc + h) * Sc + s) * DKc + d] =
                    f2bf(acc[mt][nt][r]);
            }
        }
    }
}

// ---------------------------------------------------------------------------
// Kernel 2a: rowsum partials. Waves FULLY independent, ZERO barriers:
// block = (bh, 32-q group); wave w streams ITS OWN 512-key chunk through a
// wave-private 2-slot LDS ring (32-row tiles, counted per-wave vmcnt —
// never 0 mid-loop). Grid (64,64) = 4096 blocks -> ~4 waves/SIMD even in
// the largest-L tail (the TLP every prior variant lacked).
// ---------------------------------------------------------------------------
__global__ __launch_bounds__(256) void rowsum_part_kernel(
    const int* __restrict__ L, float* __restrict__ ws)
{
    const int bh = blockIdx.x;          // 64
    const int qg = blockIdx.y;          // 64 groups of 32 q-rows
    const int b  = bh >> 4;
    const int Lb = L[b];
    const int q0 = qg * 32;
    if (q0 >= Lb) return;

    const int wave = threadIdx.x >> 6;
    const int lane = threadIdx.x & 63;
    const int l16 = lane & 15, quad = lane >> 4;

    const int kc0 = wave * 512;
    if (kc0 >= Lb) return;              // no barriers in kernel: safe
    const int kend = (kc0 + 512 < Lb) ? kc0 + 512 : Lb;

    const short* __restrict__ qarr = (const short*)(ws + QOFF) + (size_t)bh * Sc * DKc;
    const short* __restrict__ karr = (const short*)(ws + KOFF) + (size_t)bh * Sc * DKc;

    __shared__ __align__(16) short Ks[4][2][32 * 64];   // 32 KB, wave-private rings

    const int srow = lane >> 3;
    const int scol = (lane & 7) ^ srow;                 // swizzled chunk
    const short* ksrc = karr + (size_t)(kc0 + srow) * DKc + scol * 8;

    // hoist 32 q rows (2 groups of 16) as B-fragments
    bf16x8 bq[2][2];
    #pragma unroll
    for (int g = 0; g < 2; ++g) {
        const short* qr = qarr + (size_t)(q0 + g * 16 + l16) * DKc;
        bq[g][0] = *(const bf16x8*)(qr + quad * 8);
        bq[g][1] = *(const bf16x8*)(qr + 32 + quad * 8);
    }
    float lacc[2] = {0.f, 0.f};

    const int n = (kend - kc0 + 31) >> 5;   // 32-row tiles in this chunk

    auto stage = [&](int s, int ktr) {
        short* dst = &Ks[wave][s][0];
        #pragma unroll
        for (int j = 0; j < 4; ++j)
            gld_lds16(ksrc + (size_t)(ktr + j * 8) * DKc, dst + j * 512);
    };

    stage(0, 0);
    if (n > 1) stage(1, 32);

    for (int t = 0; t < n; ++t) {
        const int ktr = t << 5;
        const int kabs = kc0 + ktr;
        if (t + 1 < n) asm volatile("s_waitcnt vmcnt(4)" ::: "memory");
        else           asm volatile("s_waitcnt vmcnt(0)" ::: "memory");

        const short* B = &Ks[wave][t & 1][0];
        if (kabs + 32 <= Lb) {
            #pragma unroll
            for (int tt = 0; tt < 2; ++tt) {
                const int r = tt * 16 + l16;
                const bf16x8 alo = *(const bf16x8*)(B + r * 64 + (quad ^ (r & 7)) * 8);
                const bf16x8 ahi = *(const bf16x8*)(B + r * 64 + ((4 + quad) ^ (r & 7)) * 8);
                #pragma unroll
                for (int g = 0; g < 2; ++g) {
                    f32x4 c = {0.f, 0.f, 0.f, 0.f};
                    c = __builtin_amdgcn_mfma_f32_16x16x32_bf16(alo, bq[g][0], c, 0, 0, 0);
                    c = __builtin_amdgcn_mfma_f32_16x16x32_bf16(ahi, bq[g][1], c, 0, 0, 0);
                    lacc[g] += (ex2(c[0]) + ex2(c[1])) + (ex2(c[2]) + ex2(c[3]));
                }
            }
        } else {
            // boundary tile: mask k >= Lb (staged rows are finite proj data)
            #pragma unroll
            for (int tt = 0; tt < 2; ++tt) {
                const int r = tt * 16 + l16;
                const bf16x8 alo = *(const bf16x8*)(B + r * 64 + (quad ^ (r & 7)) * 8);
                const bf16x8 ahi = *(const bf16x8*)(B + r * 64 + ((4 + quad) ^ (r & 7)) * 8);
                #pragma unroll
                for (int g = 0; g < 2; ++g) {
                    f32x4 c = {0.f, 0.f, 0.f, 0.f};
                    c = __builtin_amdgcn_mfma_f32_16x16x32_bf16(alo, bq[g][0], c, 0, 0, 0);
                    c = __builtin_amdgcn_mfma_f32_16x16x32_bf16(ahi, bq[g][1], c, 0, 0, 0);
                    #pragma unroll
                    for (int rr = 0; rr < 4; ++rr) {
                        const bool kv = (kabs + tt * 16 + quad * 4 + rr) < Lb;
                        lacc[g] += kv ? ex2(c[rr]) : 0.f;
                    }
                }
            }
        }
        if (t + 2 < n) stage(t & 1, ktr + 64);   // refill freed slot
    }

    // sum over quads (k sub-blocks); col l16 is the q index
    #pragma unroll
    for (int g = 0; g < 2; ++g) {
        lacc[g] += __shfl_xor(lacc[g], 16, 64);
        lacc[g] += __shfl_xor(lacc[g], 32, 64);
    }
    // chunk index == wave
    float* __restrict__ rp = ws + RPOFF + ((size_t)wave * 64 + bh) * Sc;
    if (quad == 0) rp[q0 + l16]      = lacc[0];
    if (quad == 1) rp[q0 + 16 + l16] = lacc[1];
}

// ---------------------------------------------------------------------------
// Kernel 2b: liarr[q] = 1 / sum over valid 512-k-chunks of rp.
// ---------------------------------------------------------------------------
__global__ __launch_bounds__(256) void rowsum_reduce_kernel(
    const int* __restrict__ L, float* __restrict__ ws)
{
    const int bh = blockIdx.y;
    const int q  = blockIdx.x * 256 + threadIdx.x;
    const int nc = (L[bh >> 4] + 511) >> 9;
    float acc = 0.f;
    for (int c = 0; c < nc; ++c)
        acc += ws[RPOFF + ((size_t)c * 64 + bh) * Sc + q];
    ws[LIOFF + (size_t)bh * Sc + q] = 1.0f / acc;
}

// ---------------------------------------------------------------------------
// Kernel 3a: colsum partials. Mirror structure: block = (bh, 32-k group);
// wave w streams ITS OWN 512-query chunk (ring) plus a once-staged
// wave-private Lis slice (issued FIRST so the same counted vmcnt covers it).
// Zero barriers.
// ---------------------------------------------------------------------------
__global__ __launch_bounds__(256) void colsum_part_kernel(
    const int* __restrict__ L, float* __restrict__ ws)
{
    const int bh = blockIdx.x;          // 64
    const int kg = blockIdx.y;          // 64 groups of 32 k-rows
    const int b  = bh >> 4;
    const int Lb = L[b];
    const int k0 = kg * 32;
    if (k0 >= Lb) return;

    const int wave = threadIdx.x >> 6;
    const int lane = threadIdx.x & 63;
    const int l16 = lane & 15, quad = lane >> 4;

    const int qc0 = wave * 512;
    if (qc0 >= Lb) return;
    const int qend = (qc0 + 512 < Lb) ? qc0 + 512 : Lb;

    const short* __restrict__ qarr = (const short*)(ws + QOFF) + (size_t)bh * Sc * DKc;
    const short* __restrict__ karr = (const short*)(ws + KOFF) + (size_t)bh * Sc * DKc;
    const float* __restrict__ liarr = ws + LIOFF + (size_t)bh * Sc;

    __shared__ __align__(16) short Qs[4][2][32 * 64];   // 32 KB rings
    __shared__ __align__(16) float Lis[4][512];         // 8 KB, wave-private

    // hoist 32 k rows (2 groups of 16) as A-fragments
    bf16x8 ak[2][2];
    #pragma unroll
    for (int g = 0; g < 2; ++g) {
        const short* kr = karr + (size_t)(k0 + g * 16 + l16) * DKc;
        ak[g][0] = *(const bf16x8*)(kr + quad * 8);
        ak[g][1] = *(const bf16x8*)(kr + 32 + quad * 8);
    }

    // issue Lis FIRST (2 x gld_lds, 512 floats) so ring waits cover it
    #pragma unroll
    for (int j2 = 0; j2 < 2; ++j2)
        gld_lds16(liarr + qc0 + j2 * 256 + lane * 4, &Lis[wave][j2 * 256]);

    const int srow = lane >> 3;
    const int scol = (lane & 7) ^ srow;
    const short* qsrc = qarr + (size_t)(qc0 + srow) * DKc + scol * 8;

    f32x4 w[2];
    w[0] = (f32x4){0.f, 0.f, 0.f, 0.f};
    w[1] = (f32x4){0.f, 0.f, 0.f, 0.f};

    const int n = (qend - qc0 + 31) >> 5;

    auto stage = [&](int s, int qtr) {
        short* dst = &Qs[wave][s][0];
        #pragma unroll
        for (int j = 0; j < 4; ++j)
            gld_lds16(qsrc + (size_t)(qtr + j * 8) * DKc, dst + j * 512);
    };

    stage(0, 0);
    if (n > 1) stage(1, 32);

    for (int t = 0; t < n; ++t) {
        const int qtr = t << 5;
        if (t + 1 < n) asm volatile("s_waitcnt vmcnt(4)" ::: "memory");
        else           asm volatile("s_waitcnt vmcnt(0)" ::: "memory");

        const short* B = &Qs[wave][t & 1][0];
        #pragma unroll
        for (int tt = 0; tt < 2; ++tt) {
            const int r = tt * 16 + l16;
            const bf16x8 blo = *(const bf16x8*)(B + r * 64 + (quad ^ (r & 7)) * 8);
            const bf16x8 bhi = *(const bf16x8*)(B + r * 64 + ((4 + quad) ^ (r & 7)) * 8);
            const float lv = (qc0 + qtr + r < qend) ? Lis[wave][qtr + r] : 0.f;
            #pragma unroll
            for (int g = 0; g < 2; ++g) {
                f32x4 c = {0.f, 0.f, 0.f, 0.f};
                c = __builtin_amdgcn_mfma_f32_16x16x32_bf16(ak[g][0], blo, c, 0, 0, 0);
                c = __builtin_amdgcn_mfma_f32_16x16x32_bf16(ak[g][1], bhi, c, 0, 0, 0);
                #pragma unroll
                for (int rr = 0; rr < 4; ++rr)
                    w[g][rr] += ex2(c[rr]) * lv;
            }
        }
        if (t + 2 < n) stage(t & 1, qtr + 64);
    }

    // sum over l16 (q); row = g*16 + quad*4 + rr is the k index
    #pragma unroll
    for (int off = 1; off <= 8; off <<= 1)
        #pragma unroll
        for (int g = 0; g < 2; ++g)
            #pragma unroll
            for (int rr = 0; rr < 4; ++rr)
                w[g][rr] += __shfl_xor(w[g][rr], off, 64);
    if (l16 == 0) {
        float* __restrict__ cp = ws + CPOFF + ((size_t)wave * 64 + bh) * Sc;
        #pragma unroll
        for (int g = 0; g < 2; ++g)
            #pragma unroll
            for (int rr = 0; rr < 4; ++rr)
                cp[k0 + g * 16 + quad * 4 + rr] = w[g][rr];
    }
}

// ---------------------------------------------------------------------------
// Kernel 3b: warr[k] = sum over valid 512-q-chunks of cp.
// ---------------------------------------------------------------------------
__global__ __launch_bounds__(256) void colsum_reduce_kernel(
    const int* __restrict__ L, float* __restrict__ ws)
{
    const int bh = blockIdx.y;
    const int k  = blockIdx.x * 256 + threadIdx.x;
    const int nc = (L[bh >> 4] + 511) >> 9;
    float acc = 0.f;
    for (int c = 0; c < nc; ++c)
        acc += ws[CPOFF + ((size_t)c * 64 + bh) * Sc + k];
    ws[WOFF + (size_t)bh * Sc + k] = acc;
}

// ---------------------------------------------------------------------------
// Kernel 4a: partial y: yp[c][b,h,j] = sum_{s in chunk c} w[b,h,s]*x[b,s,j].
// ---------------------------------------------------------------------------
__global__ __launch_bounds__(256) void yw_part_kernel(
    const float* __restrict__ x, const int* __restrict__ L,
    float* __restrict__ ws)
{
    const int b  = blockIdx.y;
    const int j0 = blockIdx.x * 64;
    const int s0 = blockIdx.z * 128;
    const int Lb = L[b];
    if (s0 >= Lb) return;
    const int js = threadIdx.x & 63;
    const int sl = threadIdx.x >> 6;
    const float* __restrict__ warr = ws + WOFF + (size_t)b * NHc * Sc;
    const float* __restrict__ xb = x + (size_t)b * Sc * Hc;

    __shared__ float wt[128][20];
    __shared__ float red[4][16][64];

    #pragma unroll
    for (int i = 0; i < 8; ++i) {
        const int s = (threadIdx.x & 15) + 16 * i;
        const int h = threadIdx.x >> 4;
        float v = 0.f;
        if (s0 + s < Lb) v = warr[(size_t)h * Sc + s0 + s];
        wt[s][h] = v;
    }
    __syncthreads();

    float acc[16];
    #pragma unroll
    for (int h = 0; h < 16; ++h) acc[h] = 0.f;

    #pragma unroll 4
    for (int s = sl; s < 128; s += 4) {
        const float xv = xb[(size_t)(s0 + s) * Hc + j0 + js];
        const f32x4 wa = *(const f32x4*)&wt[s][0];
        const f32x4 wb = *(const f32x4*)&wt[s][4];
        const f32x4 wc = *(const f32x4*)&wt[s][8];
        const f32x4 wd = *(const f32x4*)&wt[s][12];
        #pragma unroll
        for (int h = 0; h < 4; ++h) acc[h]      += wa[h] * xv;
        #pragma unroll
        for (int h = 0; h < 4; ++h) acc[4 + h]  += wb[h] * xv;
        #pragma unroll
        for (int h = 0; h < 4; ++h) acc[8 + h]  += wc[h] * xv;
        #pragma unroll
        for (int h = 0; h < 4; ++h) acc[12 + h] += wd[h] * xv;
    }
    #pragma unroll
    for (int h = 0; h < 16; ++h) red[sl][h][js] = acc[h];
    __syncthreads();
    if (sl == 0) {
        float* __restrict__ yp = ws + YPOFF +
            ((size_t)blockIdx.z * Bc * NHc + (size_t)b * NHc) * Hc;
        #pragma unroll
        for (int h = 0; h < 16; ++h)
            yp[(size_t)h * Hc + j0 + js] =
                red[0][h][js] + red[1][h][js] + red[2][h][js] + red[3][h][js];
    }
}

// ---------------------------------------------------------------------------
// Kernel 4b: y[b,h,j] = sum over valid chunks of yp.
// ---------------------------------------------------------------------------
__global__ __launch_bounds__(256) void yw_reduce_kernel(
    const int* __restrict__ L, float* __restrict__ ws)
{
    const int b = blockIdx.y;
    const int i = blockIdx.x * 256 + threadIdx.x;   // over NHc*Hc = 16384
    const int nc = (L[b] + 127) >> 7;
    const float* __restrict__ p = ws + YPOFF + (size_t)b * NHc * Hc + i;
    float acc = 0.f;
    for (int c = 0; c < nc; ++c)
        acc += p[(size_t)c * Bc * NHc * Hc];
    ws[YOFF + (size_t)b * NHc * Hc + i] = acc;
}

// ---------------------------------------------------------------------------
// Kernel 5: csum[b,n] = sum_j y[b,h(n),j]*Wv[n,j] + bv[n]*L[b].
// ---------------------------------------------------------------------------
__global__ __launch_bounds__(256) void csum_kernel(
    const float* __restrict__ Wv, const float* __restrict__ bv,
    const int* __restrict__ L, float* __restrict__ ws)
{
    const int b = blockIdx.y;
    const int h = blockIdx.x;            // n0 = h*64, all in head h
    const int n0 = h * 64;
    const int lane = threadIdx.x & 63;
    const int wave = threadIdx.x >> 6;
    const float Lb = (float)L[b];

    __shared__ float ys[1024];
    const float* __restrict__ y = ws + YOFF + ((size_t)b * NHc + h) * Hc;
    for (int i = threadIdx.x; i < 1024; i += 256) ys[i] = y[i];
    __syncthreads();

    f32x4 yv[4];
    #pragma unroll
    for (int p = 0; p < 4; ++p) yv[p] = *(const f32x4*)&ys[p * 256 + lane * 4];

    #pragma unroll
    for (int r = 0; r < 16; ++r) {
        const int n = n0 + wave * 16 + r;
        const float* wrow = Wv + (size_t)n * Hc;
        float a = 0.f;
        #pragma unroll
        for (int p = 0; p < 4; ++p) {
            const f32x4 wv = *(const f32x4*)(wrow + p * 256 + lane * 4);
            a += wv[0]*yv[p][0] + wv[1]*yv[p][1] + wv[2]*yv[p][2] + wv[3]*yv[p][3];
        }
        #pragma unroll
        for (int off = 32; off > 0; off >>= 1) a += __shfl_xor(a, off, 64);
        if (lane == 0)
            ws[CSOFF + (size_t)b * Hc + n] = a + bv[n] * Lb;
    }
}

// ---------------------------------------------------------------------------
// Kernel 6: pooled[b,o] = (sum_n csum[b,n]*Wo[o,n]) / L[b] + bo[o].
// ---------------------------------------------------------------------------
__global__ __launch_bounds__(256) void out_kernel(
    const float* __restrict__ Wo, const float* __restrict__ bo,
    const int* __restrict__ L, const float* __restrict__ ws,
    float* __restrict__ out)
{
    const int b = blockIdx.y;
    const int o0 = blockIdx.x * 64;
    const int lane = threadIdx.x & 63;
    const int wave = threadIdx.x >> 6;
    const float linv = 1.0f / (float)L[b];

    __shared__ float cs[1024];
    const float* __restrict__ c = ws + CSOFF + (size_t)b * Hc;
    for (int i = threadIdx.x; i < 1024; i += 256) cs[i] = c[i];
    __syncthreads();

    f32x4 cv[4];
    #pragma unroll
    for (int p = 0; p < 4; ++p) cv[p] = *(const f32x4*)&cs[p * 256 + lane * 4];

    #pragma unroll
    for (int r = 0; r < 16; ++r) {
        const int o = o0 + wave * 16 + r;
        const float* wrow = Wo + (size_t)o * Hc;
        float a = 0.f;
        #pragma unroll
        for (int p = 0; p < 4; ++p) {
            const f32x4 wv = *(const f32x4*)(wrow + p * 256 + lane * 4);
            a += wv[0]*cv[p][0] + wv[1]*cv[p][1] + wv[2]*cv[p][2] + wv[3]*cv[p][3];
        }
        #pragma unroll
        for (int off = 32; off > 0; off >>= 1) a += __shfl_xor(a, off, 64);
        if (lane == 0)
            out[(size_t)b * Hc + o] = a * linv + bo[o];
    }
}

// ---------------------------------------------------------------------------
extern "C" void kernel_launch(void* const* d_in, const int* in_sizes, int n_in,
                              void* d_out, int out_size, void* d_ws, size_t ws_size,
                              hipStream_t stream)
{
    (void)in_sizes; (void)n_in; (void)out_size; (void)ws_size;
    const float* x  = (const float*)d_in[0];
    const int*   L  = (const int*)d_in[1];
    const float* Wq = (const float*)d_in[2];
    const float* Wk = (const float*)d_in[3];
    const float* Wv = (const float*)d_in[4];
    const float* bv = (const float*)d_in[5];
    const float* Wo = (const float*)d_in[6];
    const float* bo = (const float*)d_in[7];
    float* out = (float*)d_out;
    float* ws  = (float*)d_ws;

    cvt_all_kernel<<<5120, 256, 0, stream>>>(x, Wq, Wk, ws);

    dim3 gp(Hc / 128, (Bc * Sc) / 128, 2);
    proj_mfma_kernel<<<gp, 256, 0, stream>>>(L, ws);

    dim3 gr(Bc * NHc, Sc / 32);
    rowsum_part_kernel<<<gr, 256, 0, stream>>>(L, ws);
    dim3 grr(Sc / 256, Bc * NHc);
    rowsum_reduce_kernel<<<grr, 256, 0, stream>>>(L, ws);

    colsum_part_kernel<<<gr, 256, 0, stream>>>(L, ws);
    colsum_reduce_kernel<<<grr, 256, 0, stream>>>(L, ws);

    dim3 gy(Hc / 64, Bc, Sc / 128);
    yw_part_kernel<<<gy, 256, 0, stream>>>(x, L, ws);

    dim3 gyr((NHc * Hc) / 256, Bc);
    yw_reduce_kernel<<<gyr, 256, 0, stream>>>(L, ws);

    dim3 gc(NHc, Bc);
    csum_kernel<<<gc, 256, 0, stream>>>(Wv, bv, L, ws);

    dim3 go(Hc / 64, Bc);
    out_kernel<<<go, 256, 0, stream>>>(Wo, bo, L, ws, out);
}